// Round 6
// baseline (252.841 us; speedup 1.0000x reference)
//
#include <hip/hip_runtime.h>
#include <math.h>

#define HDIM 128
#define BSH 9                 // bucket shift: 512 nodes per bucket
#define CAP 10240             // per-bucket capacity slot in eb (mean 8163, sigma~90)
#define CH 4096               // edges per binning chunk
#define GEMM_BLKS 121         // gemm blocks: 391 binB + 121 gemm = 512 = 2 blocks/CU capacity

typedef __attribute__((ext_vector_type(8))) short short8;
typedef __attribute__((ext_vector_type(4))) float f32x4;

__device__ inline unsigned short bf16_hi(float f) {
    return (unsigned short)(__float_as_uint(f) >> 16);
}
__device__ inline unsigned short bf16_rn(float f) {
    unsigned int u = __float_as_uint(f);
    return (unsigned short)((u + 0x7FFF + ((u >> 16) & 1)) >> 16);
}

// ---------- 0. prep: W -> Whg/Wlg (bf16 hi + residual lo), init bucket cursors ----------
__global__ __launch_bounds__(256) void prep_kernel(
    const float* __restrict__ W, uint4* __restrict__ Whg, uint4* __restrict__ Wlg,
    int* __restrict__ bcur) {
    const int t = threadIdx.x;
    bcur[t] = t * CAP;                    // absolute reservation cursor per bucket
    for (int idx = t; idx < 2048; idx += 256) {
        const int j = idx >> 4;
        const int c = idx & 15;
        const float4* wp = (const float4*)(W + (size_t)j * HDIM + c * 8);
        float4 va = wp[0], vb = wp[1];
        float vs[8] = {va.x, va.y, va.z, va.w, vb.x, vb.y, vb.z, vb.w};
        unsigned short h[8], l[8];
        #pragma unroll
        for (int k = 0; k < 8; ++k) {
            h[k] = bf16_hi(vs[k]);
            float hf = __uint_as_float((unsigned int)h[k] << 16);
            l[k] = bf16_hi(vs[k] - hf);
        }
        uint4 hch, lch;
        hch.x = (unsigned int)h[0] | ((unsigned int)h[1] << 16);
        hch.y = (unsigned int)h[2] | ((unsigned int)h[3] << 16);
        hch.z = (unsigned int)h[4] | ((unsigned int)h[5] << 16);
        hch.w = (unsigned int)h[6] | ((unsigned int)h[7] << 16);
        lch.x = (unsigned int)l[0] | ((unsigned int)l[1] << 16);
        lch.y = (unsigned int)l[2] | ((unsigned int)l[3] << 16);
        lch.z = (unsigned int)l[4] | ((unsigned int)l[5] << 16);
        lch.w = (unsigned int)l[6] | ((unsigned int)l[7] << 16);
        Whg[idx] = hch;
        Wlg[idx] = lch;
    }
}

// ---------- gemm body (round-0 verbatim): gb[row][col] = bf16(x @ W^T) ----------
__device__ __forceinline__ void gemm_body(
    const float* __restrict__ x, const uint4* __restrict__ Whg,
    const uint4* __restrict__ Wlg, unsigned short* __restrict__ gb, int n,
    int g0, int g1, int bid, int nblk) {
    const int t = threadIdx.x;
    const int wave = t >> 6;
    const int lane = t & 63;
    const int q = lane >> 4;
    const int m = lane & 15;

    for (int grp = g0 + bid; grp < g1; grp += nblk) {
        const int rowbase = (grp << 7) + (wave << 5);

        f32x4 acc[2][8];
        #pragma unroll
        for (int mt = 0; mt < 2; ++mt)
            #pragma unroll
            for (int ct = 0; ct < 8; ++ct)
                acc[mt][ct] = (f32x4){0.f, 0.f, 0.f, 0.f};

        #pragma unroll
        for (int kk = 0; kk < 4; ++kk) {
            short8 ah[2], al[2];
            #pragma unroll
            for (int mt = 0; mt < 2; ++mt) {
                const int r = rowbase + (mt << 4) + m;
                float vs[8];
                if (r < n) {
                    const float4* xp = (const float4*)(x + (size_t)r * HDIM + (kk << 5) + (q << 3));
                    float4 va = xp[0], vb = xp[1];
                    vs[0] = va.x; vs[1] = va.y; vs[2] = va.z; vs[3] = va.w;
                    vs[4] = vb.x; vs[5] = vb.y; vs[6] = vb.z; vs[7] = vb.w;
                } else {
                    #pragma unroll
                    for (int k = 0; k < 8; ++k) vs[k] = 0.f;
                }
                #pragma unroll
                for (int k = 0; k < 8; ++k) {
                    unsigned short h = bf16_hi(vs[k]);
                    float hf = __uint_as_float((unsigned int)h << 16);
                    unsigned short lo = bf16_hi(vs[k] - hf);
                    ah[mt][k] = (short)h;
                    al[mt][k] = (short)lo;
                }
            }
            #pragma unroll
            for (int ct = 0; ct < 8; ++ct) {
                const int nn = (ct << 4) + m;
                const int fidx = (nn << 4) | ((kk << 2) + q);
                short8 bh = *(const short8*)&Whg[fidx];
                short8 bl = *(const short8*)&Wlg[fidx];
                #pragma unroll
                for (int mt = 0; mt < 2; ++mt) {
                    acc[mt][ct] = __builtin_amdgcn_mfma_f32_16x16x32_bf16(ah[mt], bh, acc[mt][ct], 0, 0, 0);
                    acc[mt][ct] = __builtin_amdgcn_mfma_f32_16x16x32_bf16(al[mt], bh, acc[mt][ct], 0, 0, 0);
                    acc[mt][ct] = __builtin_amdgcn_mfma_f32_16x16x32_bf16(ah[mt], bl, acc[mt][ct], 0, 0, 0);
                }
            }
        }

        #pragma unroll
        for (int mt = 0; mt < 2; ++mt) {
            #pragma unroll
            for (int rr = 0; rr < 4; ++rr) {
                const int grow = rowbase + (mt << 4) + (q << 2) + rr;
                if (grow < n) {
                    unsigned short* gp = gb + (size_t)grow * HDIM + m;
                    #pragma unroll
                    for (int ct = 0; ct < 8; ++ct)
                        gp[ct << 4] = bf16_rn(acc[mt][ct][rr]);
                }
            }
        }
    }
}

// ---------- binB body (capacity slots): bin edges into eb ----------
__device__ __forceinline__ void binB_body(
    const int* __restrict__ ei, int E,
    int* __restrict__ bcur, unsigned int* __restrict__ eb,
    int chunk, int* hist, int* base, int* cur) {
    const int t = threadIdx.x;
    const int c0 = chunk * CH;
    hist[t] = 0;
    __syncthreads();

    int sv[CH / 256], dv[CH / 256];
    #pragma unroll
    for (int k = 0; k < CH / 256; ++k) {
        int e = c0 + t + (k << 8);
        if (e < E) {
            sv[k] = ei[e];
            dv[k] = ei[E + e];
            atomicAdd(&hist[dv[k] >> BSH], 1);
        } else {
            dv[k] = -1;
        }
    }
    __syncthreads();
    if (hist[t] > 0) base[t] = atomicAdd(&bcur[t], hist[t]);   // absolute slot in eb
    cur[t] = 0;
    __syncthreads();
    #pragma unroll
    for (int k = 0; k < CH / 256; ++k) {
        if (dv[k] >= 0) {
            int bkt = dv[k] >> BSH;
            int o = atomicAdd(&cur[bkt], 1);
            eb[(size_t)base[bkt] + o] =
                ((unsigned int)(dv[k] & ((1 << BSH) - 1)) << 23) | (unsigned int)sv[k];
        }
    }
}

// ---------- fuseAB: binB (blocks first) || full gemm ----------
__global__ __launch_bounds__(256) void fuseAB_kernel(
    const int* __restrict__ ei, int E, int* __restrict__ bcur,
    unsigned int* __restrict__ eb,
    const float* __restrict__ x, const uint4* __restrict__ Whg,
    const uint4* __restrict__ Wlg, unsigned short* __restrict__ gb,
    int n, int nchunk, int ngroups) {
    __shared__ int s_a[256], s_b[256], s_c[256];
    const int bid = blockIdx.x;
    if (bid < nchunk)
        binB_body(ei, E, bcur, eb, bid, s_a, s_b, s_c);
    else
        gemm_body(x, Whg, Wlg, gb, n, 0, ngroups, bid - nchunk, GEMM_BLKS);
}

// ---------- binC: self-scan + single-pass reg-staged hist + CSR fill ----------
__global__ __launch_bounds__(512) void binC_kernel(
    const unsigned int* __restrict__ eb, const int* __restrict__ bcur,
    int* __restrict__ row_ptr, float* __restrict__ dinv,
    int* __restrict__ col, int n, int NB) {
    __shared__ int hist[512];
    __shared__ int cur[512];
    __shared__ int red[512];
    __shared__ int wsum[8];
    const int t = threadIdx.x;
    const int b = blockIdx.x;
    const int node0 = b << BSH;
    const size_t s0 = (size_t)b * CAP;          // source base in slotted eb
    const int cnt = bcur[b] - b * CAP;          // actual bucket count

    // o0 = sum of counts of buckets < b (bcur[k] = k*CAP + cnt_k after fuseAB)
    red[t] = (t < b) ? (bcur[t] - t * CAP) : 0;
    __syncthreads();
    #pragma unroll
    for (int off = 256; off > 0; off >>= 1) {
        if (t < off) red[t] += red[t + off];
        __syncthreads();
    }
    const int o0 = red[0];

    // stage this thread's bucket entries into registers (single eb read)
    unsigned int r[CAP / 512];
    #pragma unroll
    for (int k = 0; k < CAP / 512; ++k) {
        const int e = t + (k << 9);
        r[k] = (e < cnt) ? eb[s0 + e] : 0u;
    }

    hist[t] = 0;
    __syncthreads();
    #pragma unroll
    for (int k = 0; k < CAP / 512; ++k) {
        const int e = t + (k << 9);
        if (e < cnt) atomicAdd(&hist[r[k] >> 23], 1);
    }
    __syncthreads();
    const int v = hist[t];
    int x = v;
    #pragma unroll
    for (int off = 1; off < 64; off <<= 1) {
        int u = __shfl_up(x, off);
        if ((t & 63) >= off) x += u;
    }
    if ((t & 63) == 63) wsum[t >> 6] = x;
    __syncthreads();
    if (t < 8) {
        int y = wsum[t];
        #pragma unroll
        for (int off = 1; off < 8; off <<= 1) {
            int u = __shfl_up(y, off);
            if (t >= off) y += u;
        }
        wsum[t] = y;
    }
    __syncthreads();
    int excl = x - v + ((t >> 6) ? wsum[(t >> 6) - 1] : 0);

    int node = node0 + t;
    if (node < n) {
        row_ptr[node] = o0 + excl;
        dinv[node] = rsqrtf((float)v + 1.0f);
        if (node == n - 1) row_ptr[n] = o0 + excl + v;
    }
    cur[t] = o0 + excl;
    __syncthreads();
    #pragma unroll
    for (int k = 0; k < CAP / 512; ++k) {
        const int e = t + (k << 9);
        if (e < cnt) {
            int pos = atomicAdd(&cur[r[k] >> 23], 1);
            col[pos] = (int)(r[k] & 0x7FFFFF);
        }
    }
}

// ---------- gather: quarter-wave per edge, 16B/lane, 4-deep unroll (verbatim) ----------
#define EDGE_ACC(d, u) \
    a[0] = fmaf(d, __uint_as_float((u).x << 16), a[0]); \
    a[1] = fmaf(d, __uint_as_float((u).x & 0xffff0000u), a[1]); \
    a[2] = fmaf(d, __uint_as_float((u).y << 16), a[2]); \
    a[3] = fmaf(d, __uint_as_float((u).y & 0xffff0000u), a[3]); \
    a[4] = fmaf(d, __uint_as_float((u).z << 16), a[4]); \
    a[5] = fmaf(d, __uint_as_float((u).z & 0xffff0000u), a[5]); \
    a[6] = fmaf(d, __uint_as_float((u).w << 16), a[6]); \
    a[7] = fmaf(d, __uint_as_float((u).w & 0xffff0000u), a[7]);

__global__ __launch_bounds__(256) void gather_kernel(
    const int* __restrict__ row_ptr, const int* __restrict__ col,
    const uint4* __restrict__ gbr, const float* __restrict__ dinv,
    const float* __restrict__ bias, const float* __restrict__ prelu_a,
    float* __restrict__ out, int n) {
    const int wv = threadIdx.x >> 6;
    const int lane = threadIdx.x & 63;
    const int q = lane >> 4;
    const int l16 = lane & 15;
    const int i = blockIdx.x * 4 + wv;
    if (i >= n) return;

    const int beg = row_ptr[i];
    const int end = row_ptr[i + 1];
    const float di = dinv[i];

    float a[8];
    #pragma unroll
    for (int k = 0; k < 8; ++k) a[k] = 0.f;

    if (q == 0) {   // self term: dinv_i * h_i
        uint4 u = gbr[(size_t)i * 16 + l16];
        EDGE_ACC(di, u)
    }

    int e = beg + q;
    for (; e + 12 < end; e += 16) {        // 4 edges per quarter per iter
        int s0 = col[e];
        int s1 = col[e + 4];
        int s2 = col[e + 8];
        int s3 = col[e + 12];
        float d0 = dinv[s0], d1 = dinv[s1], d2 = dinv[s2], d3 = dinv[s3];
        uint4 u0 = gbr[(size_t)s0 * 16 + l16];
        uint4 u1 = gbr[(size_t)s1 * 16 + l16];
        uint4 u2 = gbr[(size_t)s2 * 16 + l16];
        uint4 u3 = gbr[(size_t)s3 * 16 + l16];
        EDGE_ACC(d0, u0)
        EDGE_ACC(d1, u1)
        EDGE_ACC(d2, u2)
        EDGE_ACC(d3, u3)
    }
    for (; e + 4 < end; e += 8) {          // 2 edges
        int s0 = col[e];
        int s1 = col[e + 4];
        float d0 = dinv[s0], d1 = dinv[s1];
        uint4 u0 = gbr[(size_t)s0 * 16 + l16];
        uint4 u1 = gbr[(size_t)s1 * 16 + l16];
        EDGE_ACC(d0, u0)
        EDGE_ACC(d1, u1)
    }
    if (e < end) {
        int s = col[e];
        float d = dinv[s];
        uint4 u = gbr[(size_t)s * 16 + l16];
        EDGE_ACC(d, u)
    }

    #pragma unroll
    for (int k = 0; k < 8; ++k) {
        a[k] += __shfl_xor(a[k], 16);
        a[k] += __shfl_xor(a[k], 32);
    }

    const float aa = prelu_a[0];
    const int c0 = (l16 << 3) + (q << 1);
    float2 bb = *(const float2*)(bias + c0);
    float v0 = di * a[(q << 1) + 0] + bb.x;
    float v1 = di * a[(q << 1) + 1] + bb.y;
    v0 = v0 >= 0.f ? v0 : aa * v0;
    v1 = v1 >= 0.f ? v1 : aa * v1;
    *(float2*)(out + (size_t)i * HDIM + c0) = make_float2(v0, v1);
}

extern "C" void kernel_launch(void* const* d_in, const int* in_sizes, int n_in,
                              void* d_out, int out_size, void* d_ws, size_t ws_size,
                              hipStream_t stream) {
    const float* x  = (const float*)d_in[0];
    const int*   ei = (const int*)d_in[1];   // edge_index (2, E), int32
    const float* W  = (const float*)d_in[2];
    const float* b  = (const float*)d_in[3];
    const float* pa = (const float*)d_in[4];

    const int n = in_sizes[0] / HDIM;        // 100000
    const int E = in_sizes[1] / 2;           // 1600000
    const int NB = (n + (1 << BSH) - 1) >> BSH;   // 196 buckets
    const int ngroups = (n + 127) >> 7;      // 782 gemm row-groups

    float* out = (float*)d_out;

    // workspace layout (16B-aligned first):
    //   gb   : n*128 ushort (25.6 MB) | eb : NB*CAP uint (8.0 MB, slotted)
    //   Whg  : 2048 uint4 (32 KB)     | Wlg : 2048 uint4 (32 KB)
    //   dinv : n floats | row_ptr : n+1 | col : E | bcur[256]
    unsigned short* gb      = (unsigned short*)d_ws;
    unsigned int*   eb      = (unsigned int*)(gb + (size_t)n * HDIM);
    uint4*          Whg     = (uint4*)(eb + (size_t)NB * CAP);
    uint4*          Wlg     = Whg + 2048;
    float*          dinv    = (float*)(Wlg + 2048);
    int*            row_ptr = (int*)(dinv + n);
    int*            col     = row_ptr + (n + 1);
    int*            bcur    = col + E;

    const int nchunk = (E + CH - 1) / CH;    // 391
    prep_kernel<<<1, 256, 0, stream>>>(W, Whg, Wlg, bcur);
    fuseAB_kernel<<<nchunk + GEMM_BLKS, 256, 0, stream>>>(ei, E, bcur, eb, x, Whg, Wlg, gb, n, nchunk, ngroups);
    binC_kernel<<<NB, 512, 0, stream>>>(eb, bcur, row_ptr, dinv, col, n, NB);
    gather_kernel<<<(n + 3) / 4, 256, 0, stream>>>(row_ptr, col, (const uint4*)gb, dinv, b, pa, out, n);
}

// Round 7
// 230.633 us; speedup vs baseline: 1.0963x; 1.0963x over previous
//
#include <hip/hip_runtime.h>
#include <math.h>

#define HDIM 128
#define BSH 9                 // bucket shift: 512 nodes per bucket
#define CAP 10240             // per-bucket capacity slot in eb (mean 8163, sigma~90)
#define CH 8192               // edges per binning chunk (196 chunks)
#define GEMM_BLKS 256         // gemm blocks in the fused kernel (round-5 value)

typedef __attribute__((ext_vector_type(8))) short short8;
typedef __attribute__((ext_vector_type(4))) float f32x4;

__device__ inline unsigned short bf16_hi(float f) {
    return (unsigned short)(__float_as_uint(f) >> 16);
}
__device__ inline unsigned short bf16_rn(float f) {
    unsigned int u = __float_as_uint(f);
    return (unsigned short)((u + 0x7FFF + ((u >> 16) & 1)) >> 16);
}

// ---------- 0. prep: W -> Whg/Wlg (bf16 hi + residual lo), init bucket cursors ----------
__global__ __launch_bounds__(256) void prep_kernel(
    const float* __restrict__ W, uint4* __restrict__ Whg, uint4* __restrict__ Wlg,
    int* __restrict__ bcur) {
    const int t = threadIdx.x;
    bcur[t] = t * CAP;                    // absolute reservation cursor per bucket
    for (int idx = t; idx < 2048; idx += 256) {
        const int j = idx >> 4;
        const int c = idx & 15;
        const float4* wp = (const float4*)(W + (size_t)j * HDIM + c * 8);
        float4 va = wp[0], vb = wp[1];
        float vs[8] = {va.x, va.y, va.z, va.w, vb.x, vb.y, vb.z, vb.w};
        unsigned short h[8], l[8];
        #pragma unroll
        for (int k = 0; k < 8; ++k) {
            h[k] = bf16_hi(vs[k]);
            float hf = __uint_as_float((unsigned int)h[k] << 16);
            l[k] = bf16_hi(vs[k] - hf);
        }
        uint4 hch, lch;
        hch.x = (unsigned int)h[0] | ((unsigned int)h[1] << 16);
        hch.y = (unsigned int)h[2] | ((unsigned int)h[3] << 16);
        hch.z = (unsigned int)h[4] | ((unsigned int)h[5] << 16);
        hch.w = (unsigned int)h[6] | ((unsigned int)h[7] << 16);
        lch.x = (unsigned int)l[0] | ((unsigned int)l[1] << 16);
        lch.y = (unsigned int)l[2] | ((unsigned int)l[3] << 16);
        lch.z = (unsigned int)l[4] | ((unsigned int)l[5] << 16);
        lch.w = (unsigned int)l[6] | ((unsigned int)l[7] << 16);
        Whg[idx] = hch;
        Wlg[idx] = lch;
    }
}

// ---------- gemm body (round-0 verbatim): gb[row][col] = bf16(x @ W^T) ----------
__device__ __forceinline__ void gemm_body(
    const float* __restrict__ x, const uint4* __restrict__ Whg,
    const uint4* __restrict__ Wlg, unsigned short* __restrict__ gb, int n,
    int g0, int g1, int bid, int nblk) {
    const int t = threadIdx.x;
    const int wave = t >> 6;
    const int lane = t & 63;
    const int q = lane >> 4;
    const int m = lane & 15;

    for (int grp = g0 + bid; grp < g1; grp += nblk) {
        const int rowbase = (grp << 7) + (wave << 5);

        f32x4 acc[2][8];
        #pragma unroll
        for (int mt = 0; mt < 2; ++mt)
            #pragma unroll
            for (int ct = 0; ct < 8; ++ct)
                acc[mt][ct] = (f32x4){0.f, 0.f, 0.f, 0.f};

        #pragma unroll
        for (int kk = 0; kk < 4; ++kk) {
            short8 ah[2], al[2];
            #pragma unroll
            for (int mt = 0; mt < 2; ++mt) {
                const int r = rowbase + (mt << 4) + m;
                float vs[8];
                if (r < n) {
                    const float4* xp = (const float4*)(x + (size_t)r * HDIM + (kk << 5) + (q << 3));
                    float4 va = xp[0], vb = xp[1];
                    vs[0] = va.x; vs[1] = va.y; vs[2] = va.z; vs[3] = va.w;
                    vs[4] = vb.x; vs[5] = vb.y; vs[6] = vb.z; vs[7] = vb.w;
                } else {
                    #pragma unroll
                    for (int k = 0; k < 8; ++k) vs[k] = 0.f;
                }
                #pragma unroll
                for (int k = 0; k < 8; ++k) {
                    unsigned short h = bf16_hi(vs[k]);
                    float hf = __uint_as_float((unsigned int)h << 16);
                    unsigned short lo = bf16_hi(vs[k] - hf);
                    ah[mt][k] = (short)h;
                    al[mt][k] = (short)lo;
                }
            }
            #pragma unroll
            for (int ct = 0; ct < 8; ++ct) {
                const int nn = (ct << 4) + m;
                const int fidx = (nn << 4) | ((kk << 2) + q);
                short8 bh = *(const short8*)&Whg[fidx];
                short8 bl = *(const short8*)&Wlg[fidx];
                #pragma unroll
                for (int mt = 0; mt < 2; ++mt) {
                    acc[mt][ct] = __builtin_amdgcn_mfma_f32_16x16x32_bf16(ah[mt], bh, acc[mt][ct], 0, 0, 0);
                    acc[mt][ct] = __builtin_amdgcn_mfma_f32_16x16x32_bf16(al[mt], bh, acc[mt][ct], 0, 0, 0);
                    acc[mt][ct] = __builtin_amdgcn_mfma_f32_16x16x32_bf16(ah[mt], bl, acc[mt][ct], 0, 0, 0);
                }
            }
        }

        #pragma unroll
        for (int mt = 0; mt < 2; ++mt) {
            #pragma unroll
            for (int rr = 0; rr < 4; ++rr) {
                const int grow = rowbase + (mt << 4) + (q << 2) + rr;
                if (grow < n) {
                    unsigned short* gp = gb + (size_t)grow * HDIM + m;
                    #pragma unroll
                    for (int ct = 0; ct < 8; ++ct)
                        gp[ct << 4] = bf16_rn(acc[mt][ct][rr]);
                }
            }
        }
    }
}

// ---------- binB body (capacity slots, 8K chunk): bin edges into eb ----------
__device__ __forceinline__ void binB_body(
    const int* __restrict__ ei, int E,
    int* __restrict__ bcur, unsigned int* __restrict__ eb,
    int chunk, int* hist, int* base, int* cur) {
    const int t = threadIdx.x;
    const int c0 = chunk * CH;
    hist[t] = 0;
    __syncthreads();

    int sv[CH / 256], dv[CH / 256];
    #pragma unroll
    for (int k = 0; k < CH / 256; ++k) {
        int e = c0 + t + (k << 8);
        if (e < E) {
            sv[k] = ei[e];
            dv[k] = ei[E + e];
            atomicAdd(&hist[dv[k] >> BSH], 1);
        } else {
            dv[k] = -1;
        }
    }
    __syncthreads();
    if (hist[t] > 0) base[t] = atomicAdd(&bcur[t], hist[t]);   // absolute slot in eb
    cur[t] = 0;
    __syncthreads();
    #pragma unroll
    for (int k = 0; k < CH / 256; ++k) {
        if (dv[k] >= 0) {
            int bkt = dv[k] >> BSH;
            int o = atomicAdd(&cur[bkt], 1);
            eb[(size_t)base[bkt] + o] =
                ((unsigned int)(dv[k] & ((1 << BSH) - 1)) << 23) | (unsigned int)sv[k];
        }
    }
}

// ---------- fuseAB: binB (blocks first) || full gemm ----------
__global__ __launch_bounds__(256) void fuseAB_kernel(
    const int* __restrict__ ei, int E, int* __restrict__ bcur,
    unsigned int* __restrict__ eb,
    const float* __restrict__ x, const uint4* __restrict__ Whg,
    const uint4* __restrict__ Wlg, unsigned short* __restrict__ gb,
    int n, int nchunk, int ngroups) {
    __shared__ int s_a[256], s_b[256], s_c[256];
    const int bid = blockIdx.x;
    if (bid < nchunk)
        binB_body(ei, E, bcur, eb, bid, s_a, s_b, s_c);
    else
        gemm_body(x, Whg, Wlg, gb, n, 0, ngroups, bid - nchunk, GEMM_BLKS);
}

// ---------- binC: self-scan + single-pass reg-staged hist + CSR fill ----------
__global__ __launch_bounds__(512) void binC_kernel(
    const unsigned int* __restrict__ eb, const int* __restrict__ bcur,
    int* __restrict__ row_ptr, float* __restrict__ dinv,
    int* __restrict__ col, int n, int NB) {
    __shared__ int hist[512];
    __shared__ int cur[512];
    __shared__ int red[512];
    __shared__ int wsum[8];
    const int t = threadIdx.x;
    const int b = blockIdx.x;
    const int node0 = b << BSH;
    const size_t s0 = (size_t)b * CAP;          // source base in slotted eb
    const int cnt = bcur[b] - b * CAP;          // actual bucket count

    // o0 = sum of counts of buckets < b (bcur[k] = k*CAP + cnt_k after fuseAB)
    red[t] = (t < b) ? (bcur[t] - t * CAP) : 0;
    __syncthreads();
    #pragma unroll
    for (int off = 256; off > 0; off >>= 1) {
        if (t < off) red[t] += red[t + off];
        __syncthreads();
    }
    const int o0 = red[0];

    // stage this thread's bucket entries into registers (single eb read)
    unsigned int r[CAP / 512];
    #pragma unroll
    for (int k = 0; k < CAP / 512; ++k) {
        const int e = t + (k << 9);
        r[k] = (e < cnt) ? eb[s0 + e] : 0u;
    }

    hist[t] = 0;
    __syncthreads();
    #pragma unroll
    for (int k = 0; k < CAP / 512; ++k) {
        const int e = t + (k << 9);
        if (e < cnt) atomicAdd(&hist[r[k] >> 23], 1);
    }
    __syncthreads();
    const int v = hist[t];
    int x = v;
    #pragma unroll
    for (int off = 1; off < 64; off <<= 1) {
        int u = __shfl_up(x, off);
        if ((t & 63) >= off) x += u;
    }
    if ((t & 63) == 63) wsum[t >> 6] = x;
    __syncthreads();
    if (t < 8) {
        int y = wsum[t];
        #pragma unroll
        for (int off = 1; off < 8; off <<= 1) {
            int u = __shfl_up(y, off);
            if (t >= off) y += u;
        }
        wsum[t] = y;
    }
    __syncthreads();
    int excl = x - v + ((t >> 6) ? wsum[(t >> 6) - 1] : 0);

    int node = node0 + t;
    if (node < n) {
        row_ptr[node] = o0 + excl;
        dinv[node] = rsqrtf((float)v + 1.0f);
        if (node == n - 1) row_ptr[n] = o0 + excl + v;
    }
    cur[t] = o0 + excl;
    __syncthreads();
    #pragma unroll
    for (int k = 0; k < CAP / 512; ++k) {
        const int e = t + (k << 9);
        if (e < cnt) {
            int pos = atomicAdd(&cur[r[k] >> 23], 1);
            col[pos] = (int)(r[k] & 0x7FFFFF);
        }
    }
}

// ---------- gather: quarter-wave per edge, 16B/lane, 4-deep unroll (verbatim) ----------
#define EDGE_ACC(d, u) \
    a[0] = fmaf(d, __uint_as_float((u).x << 16), a[0]); \
    a[1] = fmaf(d, __uint_as_float((u).x & 0xffff0000u), a[1]); \
    a[2] = fmaf(d, __uint_as_float((u).y << 16), a[2]); \
    a[3] = fmaf(d, __uint_as_float((u).y & 0xffff0000u), a[3]); \
    a[4] = fmaf(d, __uint_as_float((u).z << 16), a[4]); \
    a[5] = fmaf(d, __uint_as_float((u).z & 0xffff0000u), a[5]); \
    a[6] = fmaf(d, __uint_as_float((u).w << 16), a[6]); \
    a[7] = fmaf(d, __uint_as_float((u).w & 0xffff0000u), a[7]);

__global__ __launch_bounds__(256) void gather_kernel(
    const int* __restrict__ row_ptr, const int* __restrict__ col,
    const uint4* __restrict__ gbr, const float* __restrict__ dinv,
    const float* __restrict__ bias, const float* __restrict__ prelu_a,
    float* __restrict__ out, int n) {
    const int wv = threadIdx.x >> 6;
    const int lane = threadIdx.x & 63;
    const int q = lane >> 4;
    const int l16 = lane & 15;
    const int i = blockIdx.x * 4 + wv;
    if (i >= n) return;

    const int beg = row_ptr[i];
    const int end = row_ptr[i + 1];
    const float di = dinv[i];

    float a[8];
    #pragma unroll
    for (int k = 0; k < 8; ++k) a[k] = 0.f;

    if (q == 0) {   // self term: dinv_i * h_i
        uint4 u = gbr[(size_t)i * 16 + l16];
        EDGE_ACC(di, u)
    }

    int e = beg + q;
    for (; e + 12 < end; e += 16) {        // 4 edges per quarter per iter
        int s0 = col[e];
        int s1 = col[e + 4];
        int s2 = col[e + 8];
        int s3 = col[e + 12];
        float d0 = dinv[s0], d1 = dinv[s1], d2 = dinv[s2], d3 = dinv[s3];
        uint4 u0 = gbr[(size_t)s0 * 16 + l16];
        uint4 u1 = gbr[(size_t)s1 * 16 + l16];
        uint4 u2 = gbr[(size_t)s2 * 16 + l16];
        uint4 u3 = gbr[(size_t)s3 * 16 + l16];
        EDGE_ACC(d0, u0)
        EDGE_ACC(d1, u1)
        EDGE_ACC(d2, u2)
        EDGE_ACC(d3, u3)
    }
    for (; e + 4 < end; e += 8) {          // 2 edges
        int s0 = col[e];
        int s1 = col[e + 4];
        float d0 = dinv[s0], d1 = dinv[s1];
        uint4 u0 = gbr[(size_t)s0 * 16 + l16];
        uint4 u1 = gbr[(size_t)s1 * 16 + l16];
        EDGE_ACC(d0, u0)
        EDGE_ACC(d1, u1)
    }
    if (e < end) {
        int s = col[e];
        float d = dinv[s];
        uint4 u = gbr[(size_t)s * 16 + l16];
        EDGE_ACC(d, u)
    }

    #pragma unroll
    for (int k = 0; k < 8; ++k) {
        a[k] += __shfl_xor(a[k], 16);
        a[k] += __shfl_xor(a[k], 32);
    }

    const float aa = prelu_a[0];
    const int c0 = (l16 << 3) + (q << 1);
    float2 bb = *(const float2*)(bias + c0);
    float v0 = di * a[(q << 1) + 0] + bb.x;
    float v1 = di * a[(q << 1) + 1] + bb.y;
    v0 = v0 >= 0.f ? v0 : aa * v0;
    v1 = v1 >= 0.f ? v1 : aa * v1;
    *(float2*)(out + (size_t)i * HDIM + c0) = make_float2(v0, v1);
}

extern "C" void kernel_launch(void* const* d_in, const int* in_sizes, int n_in,
                              void* d_out, int out_size, void* d_ws, size_t ws_size,
                              hipStream_t stream) {
    const float* x  = (const float*)d_in[0];
    const int*   ei = (const int*)d_in[1];   // edge_index (2, E), int32
    const float* W  = (const float*)d_in[2];
    const float* b  = (const float*)d_in[3];
    const float* pa = (const float*)d_in[4];

    const int n = in_sizes[0] / HDIM;        // 100000
    const int E = in_sizes[1] / 2;           // 1600000
    const int NB = (n + (1 << BSH) - 1) >> BSH;   // 196 buckets
    const int ngroups = (n + 127) >> 7;      // 782 gemm row-groups

    float* out = (float*)d_out;

    // workspace layout (16B-aligned first):
    //   gb   : n*128 ushort (25.6 MB) | eb : NB*CAP uint (8.0 MB, slotted)
    //   Whg  : 2048 uint4 (32 KB)     | Wlg : 2048 uint4 (32 KB)
    //   dinv : n floats | row_ptr : n+1 | col : E | bcur[256]
    unsigned short* gb      = (unsigned short*)d_ws;
    unsigned int*   eb      = (unsigned int*)(gb + (size_t)n * HDIM);
    uint4*          Whg     = (uint4*)(eb + (size_t)NB * CAP);
    uint4*          Wlg     = Whg + 2048;
    float*          dinv    = (float*)(Wlg + 2048);
    int*            row_ptr = (int*)(dinv + n);
    int*            col     = row_ptr + (n + 1);
    int*            bcur    = col + E;

    const int nchunk = (E + CH - 1) / CH;    // 196
    prep_kernel<<<1, 256, 0, stream>>>(W, Whg, Wlg, bcur);
    fuseAB_kernel<<<nchunk + GEMM_BLKS, 256, 0, stream>>>(ei, E, bcur, eb, x, Whg, Wlg, gb, n, nchunk, ngroups);
    binC_kernel<<<NB, 512, 0, stream>>>(eb, bcur, row_ptr, dinv, col, n, NB);
    gather_kernel<<<(n + 3) / 4, 256, 0, stream>>>(row_ptr, col, (const uint4*)gb, dinv, b, pa, out, n);
}